// Round 6
// baseline (172.200 us; speedup 1.0000x reference)
//
#include <hip/hip_runtime.h>
#include <cstdint>

#define BATCH   2
#define NANCH   261888
#define PRE_NMS 6000
#define PROP    1000
#define NBUCK   65536
#define SEG_CAP 8192
#define ECAP    65536
#define NT      94          // ceil(6000/64)
#define NMS_THR 0.7f

typedef unsigned long long u64;
typedef unsigned int u32;

// ---- workspace layout (bytes) ----
#define META_OFF   0u                            // int[8]: [0..1]=thr bucket, [4..5]=edge count
#define BOXES_OFF  256u                          // 2*6000*16 = 192000 -> 192256
#define EDGES_OFF  192256u                       // 2*65536*4 = 524288 -> 716544
#define HIST_OFF   716544u                       // 512KB -> 1240832
#define COARSE_OFF 1240832u                      // 2*256*4 = 2KB -> 1242880 (zeroed with hist)
#define RANK_OFF   1242880u                      // 512KB -> 1767168 (fully written, no zero)
#define SEG_OFF    1767168u                      // 128KB -> 1898240
#define ZERO_N     ((524288u + 2048u) / 4u)      // hist + coarse, one contiguous zero

__global__ void k_zero(u32* p, int n) {
    int i = blockIdx.x * blockDim.x + threadIdx.x;
    if (i < n) p[i] = 0u;
}

__device__ __forceinline__ int score_bucket(float s) {
    int bk = (int)(s * 65536.0f);
    return bk < 0 ? 0 : (bk > 65535 ? 65535 : bk);
}

// fine 64K-bucket hist (global atomics) + coarse 256-chunk hist (LDS, merged once)
__global__ __launch_bounds__(256) void k_hist(const float* __restrict__ cls,
                                              int* __restrict__ hist,
                                              int* __restrict__ coarse,
                                              int* __restrict__ meta) {
    __shared__ u32 ch[256];
    int b = blockIdx.y, t = threadIdx.x;
    ch[t] = 0;
    if (blockIdx.x == 0 && t == 0) meta[4 + b] = 0;   // edge counter
    __syncthreads();
    int stride = gridDim.x * blockDim.x;
    for (int i = blockIdx.x * blockDim.x + t; i < NANCH; i += stride) {
        float s = cls[((size_t)b * NANCH + i) * 2 + 1];
        int bk = score_bucket(s);
        atomicAdd(&hist[b * NBUCK + bk], 1);
        atomicAdd(&ch[bk >> 8], 1u);
    }
    __syncthreads();
    if (ch[t]) atomicAdd(&coarse[b * 256 + t], (int)ch[t]);
}

// per-bucket rank_start (count strictly above) + threshold bucket; grid (256, BATCH)
__global__ __launch_bounds__(256) void k_ranks(const int* __restrict__ hist,
                                               const int* __restrict__ coarse,
                                               int* __restrict__ rank_start,
                                               int* __restrict__ meta) {
    __shared__ int sc[256];
    __shared__ int sh[256];
    int b = blockIdx.y, ch = blockIdx.x, t = threadIdx.x;
    sc[t] = coarse[b * 256 + t];
    __syncthreads();
    for (int off = 1; off < 256; off <<= 1) {        // sc[t] = sum_{u>=t} coarse[u]
        int add = (t + off < 256) ? sc[t + off] : 0;
        __syncthreads();
        sc[t] += add;
        __syncthreads();
    }
    int hv = hist[b * NBUCK + ch * 256 + t];
    sh[t] = hv;
    __syncthreads();
    for (int off = 1; off < 256; off <<= 1) {        // sh[t] = within-chunk sum_{u>=t}
        int add = (t + off < 256) ? sh[t + off] : 0;
        __syncthreads();
        sh[t] += add;
        __syncthreads();
    }
    int excl_ch = (ch + 1 < 256) ? sc[ch + 1] : 0;   // chunks strictly above mine
    int r = excl_ch + sh[t] - hv;                    // buckets strictly above this one
    rank_start[b * NBUCK + ch * 256 + t] = r;
    if (r < PRE_NMS && r + hv >= PRE_NMS) meta[b] = ch * 256 + t;  // unique crossing bucket
}

// scatter: post-increment rank_start itself -> returned value IS the global rank slot.
// after this kernel: rank[bk] = start(bk) + hist[bk] = start(bk-1); neighbors give bounds.
__global__ void k_scatter(const float* __restrict__ cls, const int* __restrict__ meta,
                          int* __restrict__ rank, u64* __restrict__ seg) {
    int b = blockIdx.y;
    int thr = meta[b];
    int stride = gridDim.x * blockDim.x;
    for (int i = blockIdx.x * blockDim.x + threadIdx.x; i < NANCH; i += stride) {
        float s = cls[((size_t)b * NANCH + i) * 2 + 1];
        int bk = score_bucket(s);
        if (bk >= thr) {
            int slot = atomicAdd(&rank[b * NBUCK + bk], 1);
            if (slot < SEG_CAP) {
                u32 sb = __float_as_uint(s);
                seg[b * SEG_CAP + slot] = ((u64)sb << 32) | (u32)(~(u32)i);
            }
        }
    }
}

// fused: one thread per active bucket sorts its segment (descending u64 = exact
// top_k tie order) then immediately decodes its ranks < PRE_NMS into boxes.
__global__ __launch_bounds__(256) void k_bsortbuild(
        const int* __restrict__ meta, const int* __restrict__ rank,
        u64* __restrict__ seg,
        const float4* __restrict__ anchors, const float4* __restrict__ bbox,
        float4* __restrict__ boxes) {
    #pragma clang fp contract(off)
    int b = blockIdx.y;
    int bk = blockIdx.x * 256 + threadIdx.x;
    if (bk < meta[b]) return;
    int en = rank[b * NBUCK + bk]; if (en > SEG_CAP) en = SEG_CAP;
    int st = (bk + 1 < NBUCK) ? rank[b * NBUCK + bk + 1] : 0;   // = start(bk), post-scatter
    if (st >= en) return;
    u64* sg = seg + b * SEG_CAP;
    for (int i = st; i < en - 1; ++i) {              // tiny segments (~4): selection sort
        u64 best = sg[i]; int bi = i;
        for (int j = i + 1; j < en; ++j) {
            u64 v = sg[j];
            if (v > best) { best = v; bi = j; }
        }
        if (bi != i) { sg[bi] = sg[i]; sg[i] = best; }
    }
    int lim = en < PRE_NMS ? en : PRE_NMS;
    for (int r = st; r < lim; ++r) {
        u64 key = sg[r];
        u32 idx = ~(u32)(key & 0xffffffffull);
        float4 a = anchors[(size_t)b * NANCH + idx];
        float4 d = bbox[(size_t)b * NANCH + idx];
        float dy = d.x * 0.1f, dx = d.y * 0.1f, dh = d.z * 0.2f, dw = d.w * 0.2f;
        float h = a.z - a.x;
        float w = a.w - a.y;
        float cy = a.x + 0.5f * h + dy * h;
        float cx = a.y + 0.5f * w + dx * w;
        h = h * expf(dh);
        w = w * expf(dw);
        float y1 = cy - 0.5f * h;
        float x1 = cx - 0.5f * w;
        float y2 = y1 + h;
        float x2 = x1 + w;
        y1 = fminf(fmaxf(y1, 0.f), 1.f);
        x1 = fminf(fmaxf(x1, 0.f), 1.f);
        y2 = fminf(fmaxf(y2, 0.f), 1.f);
        x2 = fminf(fmaxf(x2, 0.f), 1.f);
        boxes[b * PRE_NMS + r] = make_float4(y1, x1, y2, x2);
    }
}

// IoU > thr pairs (i<j) appended as packed edges (j<<13)|i.
// Division-skip: iou>0.7 requires inter > 0.7*max(areas); filter at 0.69 is
// conservatively safe (>1% margin vs ~1e-6 fp rounding), exact path unchanged.
__global__ __launch_bounds__(256) void k_mask(const float4* __restrict__ boxes,
                                              u32* __restrict__ edges, int* __restrict__ ecnt) {
    #pragma clang fp contract(off)
    __shared__ float4 tb[64];
    __shared__ float ta[64];
    int b = blockIdx.z;
    int T = blockIdx.y;
    if (blockIdx.x * 4 + 3 < T) return;          // fully-dead lower-triangle block
    int w = threadIdx.x >> 6, lane = threadIdx.x & 63;
    int W = blockIdx.x * 4 + w;
    if (threadIdx.x < 64) {
        int c = T * 64 + threadIdx.x;
        float4 v = (c < PRE_NMS) ? boxes[b * PRE_NMS + c] : make_float4(0.f, 0.f, 0.f, 0.f);
        tb[threadIdx.x] = v;
        ta[threadIdx.x] = (v.z - v.x) * (v.w - v.y);
    }
    __syncthreads();
    if (W < T || W >= NT) return;
    int j = W * 64 + lane;
    u64 word = 0;
    if (j < PRE_NMS) {
        float4 bj = boxes[b * PRE_NMS + j];
        float areaj = (bj.z - bj.x) * (bj.w - bj.y);
        for (int c = 0; c < 64; ++c) {
            float4 bi = tb[c];
            float ih = fminf(bi.z, bj.z) - fmaxf(bi.x, bj.x); ih = fmaxf(ih, 0.f);
            float iw = fminf(bi.w, bj.w) - fmaxf(bi.y, bj.y); iw = fmaxf(iw, 0.f);
            float inter = ih * iw;
            if (inter > 0.69f * fmaxf(ta[c], areaj)) {
                float iou = inter / (ta[c] + areaj - inter + 1e-8f);   // exact reference order
                if (iou > NMS_THR) word |= (1ull << c);
            }
        }
    }
    if (W == T) word &= (lane ? ((1ull << lane) - 1ull) : 0ull);   // keep i<j only
    while (word) {
        int c = __ffsll((unsigned long long)word) - 1;
        word &= word - 1;
        int i = T * 64 + c;
        int pos = atomicAdd(&ecnt[b], 1);
        if (pos < ECAP) edges[b * ECAP + pos] = ((u32)j << 13) | (u32)i;
    }
}

// fused: exact greedy NMS fixed point on sparse edges (all LDS) + direct output write
__global__ __launch_bounds__(256) void k_resolveout(const u32* __restrict__ edges,
                                                    const int* __restrict__ ecnt,
                                                    const float4* __restrict__ boxes,
                                                    float* __restrict__ out) {
    __shared__ unsigned char st[6016];   // 0=unknown 1=kept(final) 2=removed(final)
    __shared__ u32 cnt[6016];
    __shared__ u64 kw[NT];
    __shared__ int wp[NT + 1];
    __shared__ int changed;
    int b = blockIdx.x, t = threadIdx.x;
    int E = ecnt[b]; if (E > ECAP) E = ECAP;
    const u32* eb = edges + (size_t)b * ECAP;
    for (int i = t; i < PROP * 4; i += 256) out[b * PROP * 4 + i] = 0.f;
    for (int j = t; j < 6016; j += 256) st[j] = 1;
    __syncthreads();
    for (int k = t; k < E; k += 256) st[eb[k] >> 13] = 0;   // has suppressor -> unknown
    __syncthreads();
    while (true) {
        if (t == 0) changed = 0;
        __syncthreads();
        // removal: final-kept i suppresses unknown j (1 is never demoted -> race-safe)
        for (int k = t; k < E; k += 256) {
            u32 e = eb[k]; int i = e & 8191, j = e >> 13;
            if (st[i] == 1 && st[j] == 0) { st[j] = 2; changed = 1; }
        }
        __syncthreads();
        // promotion: unknown j with all suppressors removed -> kept
        for (int j = t; j < 6016; j += 256) cnt[j] = 0;
        __syncthreads();
        for (int k = t; k < E; k += 256) {
            u32 e = eb[k]; int i = e & 8191, j = e >> 13;
            if (st[i] != 2) atomicAdd(&cnt[j], 1u);
        }
        __syncthreads();
        for (int j = t; j < 6016; j += 256) {
            if (st[j] == 0 && cnt[j] == 0) { st[j] = 1; changed = 1; }
        }
        __syncthreads();
        if (!changed) break;
    }
    // pack kept bits per 64-word, prefix-sum ranks, scatter boxes
    if (t < NT) {
        int base = t * 64;
        int lim = PRE_NMS - base; if (lim > 64) lim = 64;
        u64 bits = 0;
        for (int l = 0; l < lim; ++l) if (st[base + l] == 1) bits |= (1ull << l);
        kw[t] = bits;
        wp[t + 1] = __popcll(bits);
    }
    if (t == 0) wp[0] = 0;
    __syncthreads();
    if (t == 0) { for (int i = 1; i <= NT; ++i) wp[i] += wp[i - 1]; }
    __syncthreads();
    float4* out4 = (float4*)(out + b * PROP * 4);
    for (int j = t; j < PRE_NMS; j += 256) {
        u64 w = kw[j >> 6];
        int bit = j & 63;
        if ((w >> bit) & 1ull) {
            int rank = wp[j >> 6] + __popcll(w & ((1ull << bit) - 1ull));
            if (rank < PROP) out4[rank] = boxes[b * PRE_NMS + j];
        }
    }
}

extern "C" void kernel_launch(void* const* d_in, const int* in_sizes, int n_in,
                              void* d_out, int out_size, void* d_ws, size_t ws_size,
                              hipStream_t stream) {
    const float*  cls     = (const float*)d_in[0];
    const float4* bbox    = (const float4*)d_in[1];
    const float4* anchors = (const float4*)d_in[2];
    float* out = (float*)d_out;
    char* w = (char*)d_ws;
    int*    meta   = (int*)(w + META_OFF);
    float4* boxes  = (float4*)(w + BOXES_OFF);
    u32*    edges  = (u32*)(w + EDGES_OFF);
    int*    hist   = (int*)(w + HIST_OFF);
    int*    coarse = (int*)(w + COARSE_OFF);
    int*    rank   = (int*)(w + RANK_OFF);
    u64*    seg    = (u64*)(w + SEG_OFF);

    k_zero<<<dim3((ZERO_N + 255) / 256), 256, 0, stream>>>((u32*)hist, ZERO_N);
    k_hist<<<dim3(256, BATCH), 256, 0, stream>>>(cls, hist, coarse, meta);
    k_ranks<<<dim3(256, BATCH), 256, 0, stream>>>(hist, coarse, rank, meta);
    k_scatter<<<dim3(256, BATCH), 256, 0, stream>>>(cls, meta, rank, seg);
    k_bsortbuild<<<dim3(256, BATCH), 256, 0, stream>>>(meta, rank, seg, anchors, bbox, boxes);
    k_mask<<<dim3(24, NT, BATCH), 256, 0, stream>>>(boxes, edges, meta + 4);
    k_resolveout<<<dim3(BATCH), 256, 0, stream>>>(edges, meta + 4, boxes, out);
}

// Round 7
// 154.540 us; speedup vs baseline: 1.1143x; 1.1143x over previous
//
#include <hip/hip_runtime.h>
#include <cstdint>

#define BATCH   2
#define NANCH   261888
#define PRE_NMS 6000
#define PROP    1000
#define NBUCK   65536
#define SEG_CAP 8192
#define ECAP    65536
#define NT      94          // ceil(6000/64)
#define NMS_THR 0.7f

typedef unsigned long long u64;
typedef unsigned int u32;

// ---- workspace layout (bytes) ----
#define META_OFF   0u                            // int[8]: [0..1]=thr bucket, [4..5]=edge count
#define BOXES_OFF  256u                          // 2*6000*16 = 192000 -> 192256
#define EDGES_OFF  192256u                       // 2*65536*4 = 524288 -> 716544
#define HIST_OFF   716544u                       // 512KB -> 1240832
#define CHS_OFF    1240832u                      // 2*256*4 = 2KB -> 1242880 (zeroed with hist)
#define RANK_OFF   1242880u                      // 512KB -> 1767168 (fully written, no zero)
#define SEG_OFF    1767168u                      // 128KB -> 1898240
#define ZERO_N     ((524288u + 2048u) / 4u)      // hist + chunksum, one contiguous zero

__global__ void k_zero(u32* p, int n) {
    int i = blockIdx.x * blockDim.x + threadIdx.x;
    if (i < n) p[i] = 0u;
}

__device__ __forceinline__ int score_bucket(float s) {
    int bk = (int)(s * 65536.0f);
    return bk < 0 ? 0 : (bk > 65535 ? 65535 : bk);
}

// fine 64K-bucket hist; single global atomic per element (round-5 proven form)
__global__ __launch_bounds__(256) void k_hist(const float2* __restrict__ cls2,
                                              int* __restrict__ hist,
                                              int* __restrict__ meta) {
    int b = blockIdx.y;
    if (blockIdx.x == 0 && threadIdx.x == 0) meta[4 + b] = 0;   // edge counter
    int stride = gridDim.x * blockDim.x;
    for (int i = blockIdx.x * blockDim.x + threadIdx.x; i < NANCH; i += stride) {
        float s = cls2[(size_t)b * NANCH + i].y;
        atomicAdd(&hist[b * NBUCK + score_bucket(s)], 1);
    }
}

// per-256-bucket chunk sums: grid (256, BATCH), coalesced
__global__ __launch_bounds__(256) void k_chunks(const int* __restrict__ hist,
                                                int* __restrict__ chunksum) {
    __shared__ int s[256];
    int b = blockIdx.y, ch = blockIdx.x, t = threadIdx.x;
    s[t] = hist[b * NBUCK + ch * 256 + t];
    __syncthreads();
    for (int off = 128; off > 0; off >>= 1) {
        if (t < off) s[t] += s[t + off];
        __syncthreads();
    }
    if (t == 0) atomicAdd(&chunksum[b * 256 + ch], s[0]);
}

// per-bucket rank_start (count strictly above) + threshold bucket; grid (256, BATCH)
__global__ __launch_bounds__(256) void k_ranks(const int* __restrict__ hist,
                                               const int* __restrict__ chunksum,
                                               int* __restrict__ rank_start,
                                               int* __restrict__ meta) {
    __shared__ int sc[256];
    __shared__ int sh[256];
    int b = blockIdx.y, ch = blockIdx.x, t = threadIdx.x;
    sc[t] = chunksum[b * 256 + t];
    __syncthreads();
    for (int off = 1; off < 256; off <<= 1) {        // sc[t] = sum_{u>=t} chunksum[u]
        int add = (t + off < 256) ? sc[t + off] : 0;
        __syncthreads();
        sc[t] += add;
        __syncthreads();
    }
    int hv = hist[b * NBUCK + ch * 256 + t];
    sh[t] = hv;
    __syncthreads();
    for (int off = 1; off < 256; off <<= 1) {        // sh[t] = within-chunk sum_{u>=t}
        int add = (t + off < 256) ? sh[t + off] : 0;
        __syncthreads();
        sh[t] += add;
        __syncthreads();
    }
    int excl_ch = (ch + 1 < 256) ? sc[ch + 1] : 0;   // chunks strictly above mine
    int r = excl_ch + sh[t] - hv;                    // buckets strictly above this one
    rank_start[b * NBUCK + ch * 256 + t] = r;
    if (r < PRE_NMS && r + hv >= PRE_NMS) meta[b] = ch * 256 + t;  // unique crossing bucket
}

// scatter: post-increment rank_start itself -> returned value IS the global rank slot.
// after this kernel: rank[bk] = start(bk) + hist[bk] = start(bk-1); neighbors give bounds.
__global__ void k_scatter(const float2* __restrict__ cls2, const int* __restrict__ meta,
                          int* __restrict__ rank, u64* __restrict__ seg) {
    int b = blockIdx.y;
    int thr = meta[b];
    int stride = gridDim.x * blockDim.x;
    for (int i = blockIdx.x * blockDim.x + threadIdx.x; i < NANCH; i += stride) {
        float s = cls2[(size_t)b * NANCH + i].y;
        int bk = score_bucket(s);
        if (bk >= thr) {
            int slot = atomicAdd(&rank[b * NBUCK + bk], 1);
            if (slot < SEG_CAP) {
                u32 sb = __float_as_uint(s);
                seg[b * SEG_CAP + slot] = ((u64)sb << 32) | (u32)(~(u32)i);
            }
        }
    }
}

// one thread per active bucket: selection sort (descending u64 = exact top_k tie order)
__global__ void k_bsort(const int* __restrict__ meta, const int* __restrict__ rank,
                        u64* __restrict__ seg) {
    int b = blockIdx.y;
    int bk = blockIdx.x * blockDim.x + threadIdx.x;
    if (bk < meta[b]) return;
    int en = rank[b * NBUCK + bk]; if (en > SEG_CAP) en = SEG_CAP;
    int st = (bk + 1 < NBUCK) ? rank[b * NBUCK + bk + 1] : 0;   // = start(bk), post-scatter
    if (st >= en - 1) return;
    u64* sg = seg + b * SEG_CAP;
    for (int i = st; i < en - 1; ++i) {
        u64 best = sg[i]; int bi = i;
        for (int j = i + 1; j < en; ++j) {
            u64 v = sg[j];
            if (v > best) { best = v; bi = j; }
        }
        if (bi != i) { sg[bi] = sg[i]; sg[i] = best; }
    }
}

// decode top-6000 rank-ordered boxes, fully parallel (exact reference math, contract off)
__global__ void k_build(const u64* __restrict__ seg,
                        const float4* __restrict__ anchors, const float4* __restrict__ bbox,
                        float4* __restrict__ boxes) {
    #pragma clang fp contract(off)
    int g = blockIdx.x * blockDim.x + threadIdx.x;
    if (g >= BATCH * PRE_NMS) return;
    int b = g / PRE_NMS, r = g % PRE_NMS;
    u64 key = seg[b * SEG_CAP + r];
    u32 idx = ~(u32)(key & 0xffffffffull);
    float4 a = anchors[(size_t)b * NANCH + idx];
    float4 d = bbox[(size_t)b * NANCH + idx];
    float dy = d.x * 0.1f, dx = d.y * 0.1f, dh = d.z * 0.2f, dw = d.w * 0.2f;
    float h = a.z - a.x;
    float w = a.w - a.y;
    float cy = a.x + 0.5f * h + dy * h;
    float cx = a.y + 0.5f * w + dx * w;
    h = h * expf(dh);
    w = w * expf(dw);
    float y1 = cy - 0.5f * h;
    float x1 = cx - 0.5f * w;
    float y2 = y1 + h;
    float x2 = x1 + w;
    y1 = fminf(fmaxf(y1, 0.f), 1.f);
    x1 = fminf(fmaxf(x1, 0.f), 1.f);
    y2 = fminf(fmaxf(y2, 0.f), 1.f);
    x2 = fminf(fmaxf(x2, 0.f), 1.f);
    boxes[b * PRE_NMS + r] = make_float4(y1, x1, y2, x2);
}

// IoU > thr pairs (i<j) appended as packed edges (j<<13)|i.
// Two-phase: branchless candidate scan (no division, pipelines cleanly), then
// exact reference-order division only on rare candidate bits (~6% of rows).
// Filter iou>0.7 => inter > 0.7*max(areas); 0.69 margin >> fp rounding error.
__global__ __launch_bounds__(256) void k_mask(const float4* __restrict__ boxes,
                                              u32* __restrict__ edges, int* __restrict__ ecnt) {
    #pragma clang fp contract(off)
    __shared__ float4 tb[64];
    __shared__ float ta[64];
    int b = blockIdx.z;
    int T = blockIdx.y;
    if (blockIdx.x * 4 + 3 < T) return;          // fully-dead lower-triangle block
    int w = threadIdx.x >> 6, lane = threadIdx.x & 63;
    int W = blockIdx.x * 4 + w;
    if (threadIdx.x < 64) {
        int c = T * 64 + threadIdx.x;
        float4 v = (c < PRE_NMS) ? boxes[b * PRE_NMS + c] : make_float4(0.f, 0.f, 0.f, 0.f);
        tb[threadIdx.x] = v;
        ta[threadIdx.x] = (v.z - v.x) * (v.w - v.y);
    }
    __syncthreads();
    if (W < T || W >= NT) return;
    int j = W * 64 + lane;
    u64 word = 0;
    if (j < PRE_NMS) {
        float4 bj = boxes[b * PRE_NMS + j];
        float areaj = (bj.z - bj.x) * (bj.w - bj.y);
        u64 cand = 0;
        #pragma unroll 4
        for (int c = 0; c < 64; ++c) {
            float4 bi = tb[c];
            float ih = fminf(bi.z, bj.z) - fmaxf(bi.x, bj.x); ih = fmaxf(ih, 0.f);
            float iw = fminf(bi.w, bj.w) - fmaxf(bi.y, bj.y); iw = fmaxf(iw, 0.f);
            float inter = ih * iw;
            if (inter > 0.69f * fmaxf(ta[c], areaj)) cand |= (1ull << c);
        }
        while (cand) {                               // rare: exact reference-order check
            int c = __ffsll((unsigned long long)cand) - 1;
            cand &= cand - 1;
            float4 bi = tb[c];
            float ih = fminf(bi.z, bj.z) - fmaxf(bi.x, bj.x); ih = fmaxf(ih, 0.f);
            float iw = fminf(bi.w, bj.w) - fmaxf(bi.y, bj.y); iw = fmaxf(iw, 0.f);
            float inter = ih * iw;
            float iou = inter / (ta[c] + areaj - inter + 1e-8f);
            if (iou > NMS_THR) word |= (1ull << c);
        }
    }
    if (W == T) word &= (lane ? ((1ull << lane) - 1ull) : 0ull);   // keep i<j only
    while (word) {
        int c = __ffsll((unsigned long long)word) - 1;
        word &= word - 1;
        int i = T * 64 + c;
        int pos = atomicAdd(&ecnt[b], 1);
        if (pos < ECAP) edges[b * ECAP + pos] = ((u32)j << 13) | (u32)i;
    }
}

// fused: exact greedy NMS fixed point on sparse edges (all LDS) + direct output write
__global__ __launch_bounds__(256) void k_resolveout(const u32* __restrict__ edges,
                                                    const int* __restrict__ ecnt,
                                                    const float4* __restrict__ boxes,
                                                    float* __restrict__ out) {
    __shared__ unsigned char st[6016];   // 0=unknown 1=kept(final) 2=removed(final)
    __shared__ u32 cnt[6016];
    __shared__ u64 kw[NT];
    __shared__ int wp[NT + 1];
    __shared__ int changed;
    int b = blockIdx.x, t = threadIdx.x;
    int E = ecnt[b]; if (E > ECAP) E = ECAP;
    const u32* eb = edges + (size_t)b * ECAP;
    for (int i = t; i < PROP * 4; i += 256) out[b * PROP * 4 + i] = 0.f;
    for (int j = t; j < 6016; j += 256) st[j] = 1;
    __syncthreads();
    for (int k = t; k < E; k += 256) st[eb[k] >> 13] = 0;   // has suppressor -> unknown
    __syncthreads();
    while (true) {
        if (t == 0) changed = 0;
        __syncthreads();
        // removal: final-kept i suppresses unknown j (1 is never demoted -> race-safe)
        for (int k = t; k < E; k += 256) {
            u32 e = eb[k]; int i = e & 8191, j = e >> 13;
            if (st[i] == 1 && st[j] == 0) { st[j] = 2; changed = 1; }
        }
        __syncthreads();
        // promotion: unknown j with all suppressors removed -> kept
        for (int j = t; j < 6016; j += 256) cnt[j] = 0;
        __syncthreads();
        for (int k = t; k < E; k += 256) {
            u32 e = eb[k]; int i = e & 8191, j = e >> 13;
            if (st[i] != 2) atomicAdd(&cnt[j], 1u);
        }
        __syncthreads();
        for (int j = t; j < 6016; j += 256) {
            if (st[j] == 0 && cnt[j] == 0) { st[j] = 1; changed = 1; }
        }
        __syncthreads();
        if (!changed) break;
    }
    // pack kept bits per 64-word, prefix-sum ranks, scatter boxes
    if (t < NT) {
        int base = t * 64;
        int lim = PRE_NMS - base; if (lim > 64) lim = 64;
        u64 bits = 0;
        for (int l = 0; l < lim; ++l) if (st[base + l] == 1) bits |= (1ull << l);
        kw[t] = bits;
        wp[t + 1] = __popcll(bits);
    }
    if (t == 0) wp[0] = 0;
    __syncthreads();
    if (t == 0) { for (int i = 1; i <= NT; ++i) wp[i] += wp[i - 1]; }
    __syncthreads();
    float4* out4 = (float4*)(out + b * PROP * 4);
    for (int j = t; j < PRE_NMS; j += 256) {
        u64 w = kw[j >> 6];
        int bit = j & 63;
        if ((w >> bit) & 1ull) {
            int rank = wp[j >> 6] + __popcll(w & ((1ull << bit) - 1ull));
            if (rank < PROP) out4[rank] = boxes[b * PRE_NMS + j];
        }
    }
}

extern "C" void kernel_launch(void* const* d_in, const int* in_sizes, int n_in,
                              void* d_out, int out_size, void* d_ws, size_t ws_size,
                              hipStream_t stream) {
    const float2* cls2    = (const float2*)d_in[0];
    const float4* bbox    = (const float4*)d_in[1];
    const float4* anchors = (const float4*)d_in[2];
    float* out = (float*)d_out;
    char* w = (char*)d_ws;
    int*    meta   = (int*)(w + META_OFF);
    float4* boxes  = (float4*)(w + BOXES_OFF);
    u32*    edges  = (u32*)(w + EDGES_OFF);
    int*    hist   = (int*)(w + HIST_OFF);
    int*    chsum  = (int*)(w + CHS_OFF);
    int*    rank   = (int*)(w + RANK_OFF);
    u64*    seg    = (u64*)(w + SEG_OFF);

    k_zero<<<dim3((ZERO_N + 255) / 256), 256, 0, stream>>>((u32*)hist, ZERO_N);
    k_hist<<<dim3(256, BATCH), 256, 0, stream>>>(cls2, hist, meta);
    k_chunks<<<dim3(256, BATCH), 256, 0, stream>>>(hist, chsum);
    k_ranks<<<dim3(256, BATCH), 256, 0, stream>>>(hist, chsum, rank, meta);
    k_scatter<<<dim3(256, BATCH), 256, 0, stream>>>(cls2, meta, rank, seg);
    k_bsort<<<dim3(NBUCK / 256, BATCH), 256, 0, stream>>>(meta, rank, seg);
    k_build<<<dim3((BATCH * PRE_NMS + 255) / 256), 256, 0, stream>>>(seg, anchors, bbox, boxes);
    k_mask<<<dim3(24, NT, BATCH), 256, 0, stream>>>(boxes, edges, meta + 4);
    k_resolveout<<<dim3(BATCH), 256, 0, stream>>>(edges, meta + 4, boxes, out);
}